// Round 4
// baseline (183.435 us; speedup 1.0000x reference)
//
#include <hip/hip_runtime.h>
#include <hip/hip_bf16.h>
#include <stdint.h>

// B=131072, T=8, E=16, V=29.  Output dtype: FLOAT32 (reference returns f32;
// rounds 2/3 proved values were right but packed as bf16 -> position-shifted
// compare). Inputs: f32 (round-1 NaN proved bf16 misread), with runtime sniff
// as insurance.
#define NVOC 29

// g_tab layout (floats):
//   sSc:  QTT[29][29] @0, QTP[29][8] @841, QPT[8][29] @1073, QPP[8][8] @1305
//   pad @1369..1371
#define OFF_LM 1372            // LM[a][u][v] at a*233 + u*29 + v  (233 coprime 32)
#define OFF_B  (1372 + 29*233) // 8129, bias[29]
#define TAB_TOTAL 8158

__device__ float g_tab[TAB_TOTAL];

__device__ __forceinline__ float b2f(__hip_bfloat16 v) { return __bfloat162float(v); }
__device__ __forceinline__ float ldin(const void* p, int i, bool isf32) {
    return isf32 ? ((const float*)p)[i] : b2f(((const __hip_bfloat16*)p)[i]);
}

// ---------------- Kernel A: build tables once into g_tab ----------------
__global__ void prep_kernel(const void* __restrict__ tok, const void* __restrict__ pos,
                            const void* __restrict__ Wk,  const void* __restrict__ Wq,
                            const void* __restrict__ Wv,  const void* __restrict__ lmW,
                            const void* __restrict__ lmb) {
    __shared__ float sTQ[29][17], sTK[29][17], sTV[29][17];
    __shared__ float sPQ[8][17],  sPK[8][17],  sPV[8][17];
    __shared__ float sLW[29][17];
    const int tid = threadIdx.x;

    // input dtype sniff on tok (f32 data: low half-words have random exponents)
    const uint32_t* tw = (const uint32_t*)tok;
    int cnt = 0;
    #pragma unroll
    for (int wi = 0; wi < 32; ++wi) {
        uint32_t x = tw[wi];
        uint32_t e0 = (x >> 7) & 0xFF, e1 = (x >> 23) & 0xFF;
        cnt += (e0 >= 96 && e0 <= 132) ? 1 : 0;
        cnt += (e1 >= 96 && e1 <= 132) ? 1 : 0;
    }
    const bool isf32 = (cnt < 54);

    for (int i = tid; i < 29 * 16; i += 256) sLW[i >> 4][i & 15] = ldin(lmW, i, isf32);

    for (int i = tid; i < 111 * 16; i += 256) {
        const int h = i & 15, rt = i >> 4;
        const void* xp; int xo; const void* wp; float* dst;
        if (rt < 29)       { xp = tok; xo = rt * 16;         wp = Wq; dst = &sTQ[rt][h]; }
        else if (rt < 58)  { xp = tok; xo = (rt - 29) * 16;  wp = Wk; dst = &sTK[rt - 29][h]; }
        else if (rt < 87)  { xp = tok; xo = (rt - 58) * 16;  wp = Wv; dst = &sTV[rt - 58][h]; }
        else if (rt < 95)  { xp = pos; xo = (rt - 87) * 16;  wp = Wq; dst = &sPQ[rt - 87][h]; }
        else if (rt < 103) { xp = pos; xo = (rt - 95) * 16;  wp = Wk; dst = &sPK[rt - 95][h]; }
        else               { xp = pos; xo = (rt - 103) * 16; wp = Wv; dst = &sPV[rt - 103][h]; }
        float s = 0.f;
        #pragma unroll
        for (int e = 0; e < 16; ++e)
            s += ldin(xp, xo + e, isf32) * ldin(wp, h * 16 + e, isf32);
        *dst = s;
    }
    __syncthreads();

    const float f = 0.25f * 1.44269504088896340736f;  // scale * log2(e)

    for (int g = blockIdx.x * 256 + tid; g < TAB_TOTAL; g += gridDim.x * 256) {
        float val = 0.f;
        if (g < 841) {
            int a = g / 29, c = g % 29; float s = 0.f;
            #pragma unroll
            for (int h = 0; h < 16; ++h) s += sTQ[a][h] * sTK[c][h];
            val = f * s;
        } else if (g < 1073) {
            int o = g - 841, a = o >> 3, u = o & 7; float s = 0.f;
            #pragma unroll
            for (int h = 0; h < 16; ++h) s += sTQ[a][h] * sPK[u][h];
            val = f * s;
        } else if (g < 1305) {
            int o = g - 1073, t = o / 29, c = o % 29; float s = 0.f;
            #pragma unroll
            for (int h = 0; h < 16; ++h) s += sPQ[t][h] * sTK[c][h];
            val = f * s;
        } else if (g < 1369) {
            int o = g - 1305, t = o >> 3, u = o & 7; float s = 0.f;
            #pragma unroll
            for (int h = 0; h < 16; ++h) s += sPQ[t][h] * sPK[u][h];
            val = f * s;
        } else if (g >= OFF_LM && g < OFF_B) {
            int o = g - OFF_LM, a = o / 233, r = o % 233;
            if (r < 232) {
                int u = r / 29, v = r % 29; float s = 0.f;
                #pragma unroll
                for (int h = 0; h < 16; ++h) s += (sTV[a][h] + sPV[u][h]) * sLW[v][h];
                val = s;
            }
        } else if (g >= OFF_B) {
            int v = g - OFF_B;
            if (v < NVOC) val = ldin(lmb, v, isf32);
        }
        g_tab[g] = val;
    }
}

// ---------------- Kernel B: 64 batches x 8 timesteps per block ----------------
// t = tid>>6 is wave-uniform -> causal trip count (t+1) paid exactly.
// s_mem is a union: first TAB_TOTAL floats = tables; after compute, the whole
// 512*29 floats = f32 output staging (logits held in regs across the overwrite).
__global__ __launch_bounds__(512, 4)
void main_kernel(const int* __restrict__ idxg, float* __restrict__ out) {
    __shared__ __attribute__((aligned(16))) float s_mem[512 * NVOC];  // 59392 B
    __shared__ int sIdx[512];

    const int tid = threadIdx.x;
    const int blk = blockIdx.x;

    for (int i = tid; i < TAB_TOTAL; i += 512) s_mem[i] = g_tab[i];
    sIdx[tid] = idxg[blk * 512 + tid];
    __syncthreads();

    const int t  = tid >> 6;   // 0..7, uniform per wave
    const int lb = tid & 63;   // local batch

    int iu[8];
    #pragma unroll
    for (int u = 0; u < 8; ++u) iu[u] = sIdx[lb * 8 + u];
    const int it = iu[t];

    // scores (log2 domain, scale folded); mask -1e30 -> exp2 == 0
    float w[8];
    #pragma unroll
    for (int u = 0; u < 8; ++u) {
        float wu = s_mem[it * 29 + iu[u]]
                 + s_mem[841 + it * 8 + u]
                 + s_mem[1073 + t * 29 + iu[u]]
                 + s_mem[1305 + t * 8 + u];
        w[u] = (u <= t) ? wu : -1.0e30f;
    }
    float mx = w[0];
    #pragma unroll
    for (int u = 1; u < 8; ++u) mx = fmaxf(mx, w[u]);
    float ssum = 0.f;
    #pragma unroll
    for (int u = 0; u < 8; ++u) { float e = exp2f(w[u] - mx); w[u] = e; ssum += e; }
    const float inv = 1.0f / ssum;

    float acc[NVOC];
    #pragma unroll
    for (int v = 0; v < NVOC; ++v) acc[v] = 0.f;
    #pragma unroll
    for (int u = 0; u < 8; ++u) if (u <= t) {     // wave-uniform trips
        const float pu = w[u];
        const int base = OFF_LM + iu[u] * 233 + u * 29;
        #pragma unroll
        for (int v = 0; v < NVOC; ++v) acc[v] = fmaf(pu, s_mem[base + v], acc[v]);
    }
    // finalize logits into registers BEFORE the union overwrite
    #pragma unroll
    for (int v = 0; v < NVOC; ++v) acc[v] = fmaf(acc[v], inv, s_mem[OFF_B + v]);
    __syncthreads();

    // stage f32 output rows, then coalesced block store
    const int orow = (lb * 8 + t) * NVOC;
    #pragma unroll
    for (int v = 0; v < NVOC; ++v) s_mem[orow + v] = acc[v];
    __syncthreads();

    const uint4* src = (const uint4*)s_mem;           // 512*29*4 B = 3712 uint4
    uint4* dst = (uint4*)(out + (size_t)blk * (512 * NVOC));
    for (int i = tid; i < 3712; i += 512) dst[i] = src[i];
}

extern "C" void kernel_launch(void* const* d_in, const int* in_sizes, int n_in,
                              void* d_out, int out_size, void* d_ws, size_t ws_size,
                              hipStream_t stream) {
    const int* idx = (const int*)d_in[0];
    const void* tok = d_in[1];
    const void* pos = d_in[2];
    const void* Wk  = d_in[3];
    const void* Wq  = d_in[4];
    const void* Wv  = d_in[5];
    const void* lmW = d_in[6];
    const void* lmb = d_in[7];
    float* out = (float*)d_out;                 // FLOAT32 output

    const int B = in_sizes[0] / 8;              // 131072
    const int nblk = B / 64;                    // 2048

    hipLaunchKernelGGL(prep_kernel, dim3(16), dim3(256), 0, stream,
                       tok, pos, Wk, Wq, Wv, lmW, lmb);
    hipLaunchKernelGGL(main_kernel, dim3(nblk), dim3(512), 0, stream,
                       idx, out);
}